// Round 1
// baseline (2239.055 us; speedup 1.0000x reference)
//
#include <hip/hip_runtime.h>
#include <stdint.h>

typedef __attribute__((ext_vector_type(8))) short           s16x8;
typedef __attribute__((ext_vector_type(8))) unsigned short  u16x8;
typedef __attribute__((ext_vector_type(4))) unsigned short  u16x4;
typedef __attribute__((ext_vector_type(4))) float           f32x4;

#define DN  512
#define BKS 32
#define LDT 40   // padded LDS leading dim (elements)

__device__ __forceinline__ float bf2f(unsigned short u) {
  union { unsigned int i; float f; } v; v.i = ((unsigned int)u) << 16; return v.f;
}
__device__ __forceinline__ unsigned short f2bf(float f) {
  union { float f; unsigned int i; } v; v.f = f;
  unsigned int i = v.i;
  return (unsigned short)((i + 0x7fffu + ((i >> 16) & 1u)) >> 16);
}

// Computes D = Sa + Sb + Sa @ Sb  (all 512x512), D stored bf16 row-major.
// F32 sources are scaled by -1/1000 on load (Sa = -A/1000).
template<bool F32>
__global__ __launch_bounds__(256)
void combine_kernel(const void* __restrict__ a_vp, long long a_str,
                    const void* __restrict__ b_vp, long long b_str,
                    unsigned short* __restrict__ d_base, long long d_str)
{
  __shared__ __align__(16) unsigned short sA [128 * LDT]; // [m][k]
  __shared__ __align__(16) unsigned short sBt[128 * LDT]; // [n][k] (B transposed)

  const int j    = blockIdx.y;
  const int tm   = blockIdx.x >> 2;
  const int tn   = blockIdx.x & 3;
  const int tid  = threadIdx.x;
  const int w    = tid >> 6;
  const int lane = tid & 63;
  const int lq   = lane >> 4;   // quad 0..3
  const int lr   = lane & 15;

  const float scale = -0.001f;

  const float* Af = nullptr; const float* Bf = nullptr;
  const unsigned short* Ah = nullptr; const unsigned short* Bh = nullptr;
  if (F32) {
    Af = (const float*)a_vp + (long long)j * a_str;
    Bf = (const float*)b_vp + (long long)j * b_str;
  } else {
    Ah = (const unsigned short*)a_vp + (long long)j * a_str;
    Bh = (const unsigned short*)b_vp + (long long)j * b_str;
  }

  f32x4 acc[4][4] = {};

  const int wm = (w & 1) * 64;
  const int wn = (w >> 1) * 64;

  for (int kt = 0; kt < DN / BKS; ++kt) {
    const int k0 = kt * BKS;

    // ---- stage A tile: sA[m][k], 128x32
    #pragma unroll
    for (int q = 0; q < 2; ++q) {
      const int rl = (w * 2 + q) * 16 + (lane >> 2);
      const int kc = (lane & 3) * 8;
      const size_t g = (size_t)(tm * 128 + rl) * DN + k0 + kc;
      u16x8 hv;
      if (F32) {
        f32x4 v0 = *(const f32x4*)(Af + g);
        f32x4 v1 = *(const f32x4*)(Af + g + 4);
        #pragma unroll
        for (int e = 0; e < 4; ++e) { hv[e] = f2bf(v0[e] * scale); hv[4 + e] = f2bf(v1[e] * scale); }
      } else {
        hv = *(const u16x8*)(Ah + g);
      }
      *(u16x8*)&sA[rl * LDT + kc] = hv;
    }

    // ---- stage B tile transposed: sBt[n][k]  (B rows k0..k0+31, cols tn*128..+128)
    {
      const int n4 = (tid & 31) * 4;
      const int k4 = (tid >> 5) * 4;
      unsigned short vs[4][4];
      #pragma unroll
      for (int r = 0; r < 4; ++r) {
        const size_t g = (size_t)(k0 + k4 + r) * DN + tn * 128 + n4;
        if (F32) {
          f32x4 v = *(const f32x4*)(Bf + g);
          #pragma unroll
          for (int c = 0; c < 4; ++c) vs[r][c] = f2bf(v[c] * scale);
        } else {
          u16x4 v = *(const u16x4*)(Bh + g);
          #pragma unroll
          for (int c = 0; c < 4; ++c) vs[r][c] = v[c];
        }
      }
      #pragma unroll
      for (int c = 0; c < 4; ++c) {
        u16x4 col = { vs[0][c], vs[1][c], vs[2][c], vs[3][c] };
        *(u16x4*)&sBt[(n4 + c) * LDT + k4] = col;
      }
    }

    __syncthreads();

    s16x8 av[4], bv[4];
    #pragma unroll
    for (int mt = 0; mt < 4; ++mt)
      av[mt] = *(const s16x8*)&sA[(wm + mt * 16 + lr) * LDT + lq * 8];
    #pragma unroll
    for (int nt = 0; nt < 4; ++nt)
      bv[nt] = *(const s16x8*)&sBt[(wn + nt * 16 + lr) * LDT + lq * 8];

    #pragma unroll
    for (int mt = 0; mt < 4; ++mt)
      #pragma unroll
      for (int nt = 0; nt < 4; ++nt)
        acc[mt][nt] = __builtin_amdgcn_mfma_f32_16x16x32_bf16(av[mt], bv[nt], acc[mt][nt], 0, 0, 0);

    __syncthreads();
  }

  // ---- epilogue: D = acc + Sa + Sb, bf16 store (C/D layout: row=quad*4+r, col=lr)
  unsigned short* D = d_base + (long long)j * d_str;
  #pragma unroll
  for (int mt = 0; mt < 4; ++mt) {
    #pragma unroll
    for (int nt = 0; nt < 4; ++nt) {
      #pragma unroll
      for (int r = 0; r < 4; ++r) {
        const int row = tm * 128 + wm + mt * 16 + lq * 4 + r;
        const int col = tn * 128 + wn + nt * 16 + lr;
        const size_t g = (size_t)row * DN + col;
        float add;
        if (F32) add = Af[g] * scale + Bf[g] * scale;
        else     add = bf2f(Ah[g]) + bf2f(Bh[g]);
        D[g] = f2bf(acc[mt][nt][r] + add);
      }
    }
  }
}

__global__ __launch_bounds__(256) void copy_kernel(const uint4* __restrict__ src, uint4* __restrict__ dst) {
  const int idx = blockIdx.x * 256 + threadIdx.x;  // grid sized exactly
  dst[idx] = src[idx];
}

__global__ __launch_bounds__(256) void finalize_kernel(const unsigned short* __restrict__ C, float* __restrict__ out) {
  const int idx = blockIdx.x * 256 + threadIdx.x;
  const int row = idx >> 9, col = idx & 511;
  out[idx] = ((row == col) ? 1.0f : 0.0f) + bf2f(C[idx]);
}

extern "C" void kernel_launch(void* const* d_in, const int* in_sizes, int n_in,
                              void* d_out, int out_size, void* d_ws, size_t ws_size,
                              hipStream_t stream)
{
  (void)in_sizes; (void)n_in; (void)d_ws; (void)ws_size; (void)out_size;

  char* p = (char*)d_in[0];                 // 1000 MiB fp32 input; also our arena (restored each call)
  const float* A = (const float*)d_in[0];
  const size_t MB = 1ull << 20;
  const long long S = 262144;               // elements per 512x512 matrix

  // ---------- Level 1: fp32 pairs -> bf16, in-place compaction from the top ----------
  // pair j combines factors f_{2j}=M_{999-2j}, f_{2j+1}=M_{998-2j};
  // C1_j home: byte offset 1000MiB - (j+1)*0.5MiB  (descending). First 2 pairs via d_out scratch.
  const int j0s[5] = {0, 2, 8, 32, 128};
  const int j1s[5] = {2, 8, 32, 128, 500};
  for (int b = 0; b < 5; ++b) {
    const int j0 = j0s[b], n = j1s[b] - j0s[b];
    const float* abase = A + (size_t)(999 - 2 * j0) * S;
    const float* bbase = A + (size_t)(998 - 2 * j0) * S;
    unsigned short* dbase; long long dstr;
    if (b == 0) { dbase = (unsigned short*)d_out;                                dstr =  S; }
    else        { dbase = (unsigned short*)(p + 1000 * MB) - (size_t)(j0 + 1) * S; dstr = -S; }
    combine_kernel<true><<<dim3(16, n), 256, 0, stream>>>(
        (const void*)abase, -2 * S, (const void*)bbase, -2 * S, dbase, dstr);
    if (b == 0) {
      // move the two d_out-scratch results to their homes (region [999MiB,1000MiB) is dead)
      copy_kernel<<<dim3(128), 256, 0, stream>>>((const uint4*)d_out,
                                                 (uint4*)(p + 999 * MB + 512 * 1024));
      copy_kernel<<<dim3(128), 256, 0, stream>>>((const uint4*)((char*)d_out + 512 * 1024),
                                                 (uint4*)(p + 999 * MB));
    }
  }

  unsigned short* R0 = (unsigned short*)(p + 0 * MB);    // region [0,   125) MiB
  unsigned short* R1 = (unsigned short*)(p + 125 * MB);  // region [125, 187.5)
  unsigned short* R2 = (unsigned short*)(p + 200 * MB);  // region [200, 231.5)
  unsigned short* L1base_a = (unsigned short*)(p + 999 * MB + 512 * 1024); // C1_0 home
  unsigned short* L1base_b = (unsigned short*)(p + 999 * MB);              // C1_1 home

  // ---------- Level 2: 500 -> 250 (inputs descending in memory) ----------
  combine_kernel<false><<<dim3(16, 250), 256, 0, stream>>>(L1base_a, -2 * S, L1base_b, -2 * S, R0, S);
  // ---------- Level 3: 250 -> 125 ----------
  combine_kernel<false><<<dim3(16, 125), 256, 0, stream>>>(R0, 2 * S, R0 + S, 2 * S, R1, S);
  // ---------- Level 4: 125 -> 62 pairs + passthrough (slot 124 -> out slot 62) ----------
  combine_kernel<false><<<dim3(16, 62), 256, 0, stream>>>(R1, 2 * S, R1 + S, 2 * S, R2, S);
  copy_kernel<<<dim3(128), 256, 0, stream>>>((const uint4*)(R1 + (size_t)124 * S), (uint4*)(R2 + (size_t)62 * S));
  // ---------- Level 5: 63 -> 31 pairs + passthrough (slot 62 -> out slot 31) ----------
  combine_kernel<false><<<dim3(16, 31), 256, 0, stream>>>(R2, 2 * S, R2 + S, 2 * S, R0, S);
  copy_kernel<<<dim3(128), 256, 0, stream>>>((const uint4*)(R2 + (size_t)62 * S), (uint4*)(R0 + (size_t)31 * S));
  // ---------- Level 6: 32 -> 16 ----------
  combine_kernel<false><<<dim3(16, 16), 256, 0, stream>>>(R0, 2 * S, R0 + S, 2 * S, R1, S);
  // ---------- Level 7: 16 -> 8 ----------
  combine_kernel<false><<<dim3(16, 8), 256, 0, stream>>>(R1, 2 * S, R1 + S, 2 * S, R2, S);
  // ---------- Level 8: 8 -> 4 ----------
  combine_kernel<false><<<dim3(16, 4), 256, 0, stream>>>(R2, 2 * S, R2 + S, 2 * S, R0, S);
  // ---------- Level 9: 4 -> 2 ----------
  combine_kernel<false><<<dim3(16, 2), 256, 0, stream>>>(R0, 2 * S, R0 + S, 2 * S, R1, S);
  // ---------- Level 10: 2 -> 1 ----------
  combine_kernel<false><<<dim3(16, 1), 256, 0, stream>>>(R1, 2 * S, R1 + S, 2 * S, R2, S);

  // ---------- finalize: X = I + C_final (fp32) ----------
  finalize_kernel<<<dim3(1024), 256, 0, stream>>>(R2, (float*)d_out);
}